// Round 1
// baseline (352.179 us; speedup 1.0000x reference)
//
#include <hip/hip_runtime.h>
#include <math.h>

// GaussianModel projection pre-pass — 4 Gaussians per thread, all memory
// traffic as aligned float4 (16B/lane coalescing sweet spot).
//
// Reference (JAX):
//   pos_view = clip((p - t) @ R^T, -100, 100)
//   valid    = 0.1 < pos_view.z < 10
//   z        = clip(pos_view.z, 0.1, 10)
//   x        = clip(pv.x*FX/z + W/2, -1000, W+1000)
//   y        = clip(-(pv.y*FY/z) + H/2, -1000, H+1000)
//   cov2d    = [[clip(sx^2+1e-4,1e-6,1e6), 1e-6],[1e-6, clip(sy^2+1e-4,...)]]
//              sx = max(scale.x,1e-3)*FX/z, sy = max(scale.y,1e-3)*FY/z
//   colors clipped to [0,1]; opacity -> sigmoid; mask -> 1.0/0.0
// Outputs concatenated flat (float32):
//   [0,3N) proj | [3N,7N) cov2d | [7N,10N) colors | [10N,11N) opa | [11N,12N) mask
//
// N == 4,000,000 (divisible by 4); every section base (3N,7N,10N,11N floats)
// is 16B-aligned, so all float4 accesses below are aligned.

#define FXc 500.0f

__global__ __launch_bounds__(256) void gs_project4(
    const float4* __restrict__ pos4,
    const float4* __restrict__ scl4,
    const float4* __restrict__ col4,
    const float4* __restrict__ opa4,
    const float* __restrict__ vm,
    const int* __restrict__ pw,
    const int* __restrict__ ph,
    float* __restrict__ out,
    int N, int N4)
{
    int u = blockIdx.x * blockDim.x + threadIdx.x;
    if (u >= N4) return;

    // viewmat row-major 4x4; R = vm[:3,:3], t = vm[:3,3]. Uniform -> s_loads.
    float r00 = vm[0], r01 = vm[1], r02 = vm[2],  t0 = vm[3];
    float r10 = vm[4], r11 = vm[5], r12 = vm[6],  t1 = vm[7];
    float r20 = vm[8], r21 = vm[9], r22 = vm[10], t2 = vm[11];
    float W = (float)(*pw), H = (float)(*ph);

    // 4 Gaussians = 12 floats = 3 float4 per array (48B/thread, coalesced).
    size_t b3 = 3*(size_t)u;
    float4 pA = pos4[b3+0], pB = pos4[b3+1], pC = pos4[b3+2];
    float4 sA = scl4[b3+0], sB = scl4[b3+1], sC = scl4[b3+2];
    float4 cA = col4[b3+0], cB = col4[b3+1], cC = col4[b3+2];
    float4 oV = opa4[u];

    // De-interleave xyz triples.
    float px[4] = {pA.x, pA.w, pB.z, pC.y};
    float py[4] = {pA.y, pB.x, pB.w, pC.z};
    float pz[4] = {pA.z, pB.y, pC.x, pC.w};
    float s0[4] = {sA.x, sA.w, sB.z, sC.y};
    float s1[4] = {sA.y, sB.x, sB.w, sC.z};
    float ox[4] = {oV.x, oV.y, oV.z, oV.w};

    float X[4], Y[4], Z[4], C00[4], C11[4], VLD[4], SIG[4];
    #pragma unroll
    for (int j = 0; j < 4; ++j) {
        float dx = px[j] - t0, dy = py[j] - t1, dz = pz[j] - t2;
        float v0 = r00*dx + r01*dy + r02*dz;
        float v1 = r10*dx + r11*dy + r12*dz;
        float v2 = r20*dx + r21*dy + r22*dz;
        v0 = fminf(fmaxf(v0, -100.0f), 100.0f);
        v1 = fminf(fmaxf(v1, -100.0f), 100.0f);
        v2 = fminf(fmaxf(v2, -100.0f), 100.0f);

        VLD[j] = (v2 > 0.1f && v2 < 10.0f) ? 1.0f : 0.0f;
        float z   = fminf(fmaxf(v2, 0.1f), 10.0f);
        float fxz = FXc / z;   // FX == FY == 500

        X[j] = fminf(fmaxf(v0 * fxz + 0.5f * W, -1000.0f), W + 1000.0f);
        Y[j] = fminf(fmaxf(0.5f * H - v1 * fxz, -1000.0f), H + 1000.0f);
        Z[j] = v2;

        float sx = fmaxf(s0[j], 0.001f) * fxz;
        float sy = fmaxf(s1[j], 0.001f) * fxz;
        C00[j] = fminf(fmaxf(sx*sx + 1e-4f, 1e-6f), 1e6f);
        C11[j] = fminf(fmaxf(sy*sy + 1e-4f, 1e-6f), 1e6f);

        SIG[j] = 1.0f / (1.0f + __expf(-ox[j]));
    }

    float4* outp = reinterpret_cast<float4*>(out);
    size_t N4f = (size_t)N4;   // N/4, float4 units per N floats = N/4

    // proj_points: float4 index 3u..3u+2
    outp[b3+0] = make_float4(X[0], Y[0], Z[0], X[1]);
    outp[b3+1] = make_float4(Y[1], Z[1], X[2], Y[2]);
    outp[b3+2] = make_float4(Z[2], X[3], Y[3], Z[3]);

    // cov2d: base 3N floats = 3*N4f float4; 4 float4 per thread
    size_t cb = 3*N4f + 4*(size_t)u;
    outp[cb+0] = make_float4(C00[0], 1e-6f, 1e-6f, C11[0]);
    outp[cb+1] = make_float4(C00[1], 1e-6f, 1e-6f, C11[1]);
    outp[cb+2] = make_float4(C00[2], 1e-6f, 1e-6f, C11[2]);
    outp[cb+3] = make_float4(C00[3], 1e-6f, 1e-6f, C11[3]);

    // colors clipped: base 7N floats = 7*N4f float4
    size_t ob = 7*N4f + b3;
    float cr[12] = {cA.x,cA.y,cA.z,cA.w, cB.x,cB.y,cB.z,cB.w, cC.x,cC.y,cC.z,cC.w};
    #pragma unroll
    for (int j = 0; j < 12; ++j) cr[j] = fminf(fmaxf(cr[j], 0.0f), 1.0f);
    outp[ob+0] = make_float4(cr[0], cr[1], cr[2],  cr[3]);
    outp[ob+1] = make_float4(cr[4], cr[5], cr[6],  cr[7]);
    outp[ob+2] = make_float4(cr[8], cr[9], cr[10], cr[11]);

    // sigmoid(opacity): base 10N floats = 10*N4f float4
    outp[10*N4f + (size_t)u] = make_float4(SIG[0], SIG[1], SIG[2], SIG[3]);
    // valid mask: base 11N floats
    outp[11*N4f + (size_t)u] = make_float4(VLD[0], VLD[1], VLD[2], VLD[3]);
}

extern "C" void kernel_launch(void* const* d_in, const int* in_sizes, int n_in,
                              void* d_out, int out_size, void* d_ws, size_t ws_size,
                              hipStream_t stream) {
    const float4* pos = (const float4*)d_in[0];
    const float4* scl = (const float4*)d_in[1];
    // d_in[2] rotations: UNUSED by reference
    const float4* col = (const float4*)d_in[3];
    const float4* opa = (const float4*)d_in[4];
    const float*  vm  = (const float*)d_in[5];
    // d_in[6] projmat: UNUSED by reference
    const int*    pw  = (const int*)d_in[7];
    const int*    ph  = (const int*)d_in[8];

    int N  = in_sizes[0] / 3;   // in_sizes[0] = 3N floats
    int N4 = N / 4;             // N == 4,000,000 -> divisible by 4
    int blocks = (N4 + 255) / 256;
    gs_project4<<<blocks, 256, 0, stream>>>(pos, scl, col, opa, vm, pw, ph,
                                            (float*)d_out, N, N4);
}

// Round 2
// 341.168 us; speedup vs baseline: 1.0323x; 1.0323x over previous
//
#include <hip/hip_runtime.h>
#include <math.h>

// GaussianModel projection pre-pass — LDS-staged so EVERY global memory
// instruction is fully coalesced (16B/lane x 64 lanes unit-stride = 1 KB,
// full cache lines), matching the access pattern the rocclr fill kernel
// uses to hit 6.6 TB/s on this chip.
//
// Layout notes:
//  - 1 Gaussian per thread, 256/block -> 15625 full blocks (N = 4,000,000).
//  - xyz-interleaved sections (pos/scl/col in; proj/colors out) go through
//    LDS: global side is float4 unit-stride (192 f4 per block, waves 0-2);
//    LDS side is stride-3 scalar (3 invertible mod 32 -> only the free
//    2-way lane aliasing, no bank conflicts).
//  - cov2d (4 floats/G), opacity, mask are naturally unit-stride per
//    thread -> stored direct from registers.
//
// Reference (JAX):
//   pos_view = clip((p - t) @ R^T, -100, 100)
//   valid    = 0.1 < pos_view.z < 10
//   z        = clip(pos_view.z, 0.1, 10)
//   x        = clip(pv.x*FX/z + W/2, -1000, W+1000)
//   y        = clip(-(pv.y*FY/z) + H/2, -1000, H+1000)
//   cov2d    = [[clip(sx^2+1e-4,1e-6,1e6), 1e-6],[1e-6, clip(sy^2+1e-4,...)]]
//              sx = max(scale.x,1e-3)*FX/z, sy = max(scale.y,1e-3)*FY/z
//   colors clipped to [0,1]; opacity -> sigmoid; mask -> 1.0/0.0
// Outputs concatenated flat (float32):
//   [0,3N) proj | [3N,7N) cov2d | [7N,10N) colors | [10N,11N) opa | [11N,12N) mask

#define FXc 500.0f

__global__ __launch_bounds__(256) void gs_project_lds(
    const float4* __restrict__ pos4,
    const float4* __restrict__ scl4,
    const float4* __restrict__ col4,
    const float*  __restrict__ opa,
    const float*  __restrict__ vm,
    const int* __restrict__ pw,
    const int* __restrict__ ph,
    float* __restrict__ out,
    int N)
{
    const int t  = threadIdx.x;
    const int gb = blockIdx.x << 8;        // Gaussian base (256 per block)
    const int i  = gb + t;                 // my Gaussian (global)
    const int fb = blockIdx.x * 192;       // float4 base into 3-float sections
    const int Nq = N >> 2;                 // N/4 = f4 count per N floats

    __shared__ float4 lin4[576];           // pos | scl | col   (9 KB)
    __shared__ float4 lout4[384];          // proj | colc       (6 KB)
    float* lin  = reinterpret_cast<float*>(lin4);
    float* lout = reinterpret_cast<float*>(lout4);

    // ---- stage inputs: fully-coalesced float4 loads (waves 0-2 only) ----
    if (t < 192) {
        const int gi = fb + t;             // < 3*Nq for all full blocks
        if (gi < 3 * Nq) {
            lin4[t]       = pos4[gi];
            lin4[192 + t] = scl4[gi];
            lin4[384 + t] = col4[gi];
        }
    }
    // opacity: unit-stride dword load, already coalesced
    float o = (i < N) ? opa[i] : 0.0f;
    __syncthreads();

    // viewmat row-major 4x4; R = vm[:3,:3], tr = vm[:3,3]. Uniform -> s_loads.
    float r00 = vm[0], r01 = vm[1], r02 = vm[2],  t0 = vm[3];
    float r10 = vm[4], r11 = vm[5], r12 = vm[6],  t1 = vm[7];
    float r20 = vm[8], r21 = vm[9], r22 = vm[10], t2 = vm[11];
    float W = (float)(*pw), H = (float)(*ph);

    // ---- gather my Gaussian from LDS (stride-3: conflict-free) ----
    float px = lin[3*t + 0],   py = lin[3*t + 1],   pz = lin[3*t + 2];
    float s0 = lin[768 + 3*t], s1 = lin[768 + 3*t + 1];
    float c0 = lin[1536 + 3*t], c1 = lin[1536 + 3*t + 1], c2 = lin[1536 + 3*t + 2];

    // ---- compute ----
    float dx = px - t0, dy = py - t1, dz = pz - t2;
    float v0 = r00*dx + r01*dy + r02*dz;
    float v1 = r10*dx + r11*dy + r12*dz;
    float v2 = r20*dx + r21*dy + r22*dz;
    v0 = fminf(fmaxf(v0, -100.0f), 100.0f);
    v1 = fminf(fmaxf(v1, -100.0f), 100.0f);
    v2 = fminf(fmaxf(v2, -100.0f), 100.0f);

    float vld = (v2 > 0.1f && v2 < 10.0f) ? 1.0f : 0.0f;
    float z   = fminf(fmaxf(v2, 0.1f), 10.0f);
    float fxz = FXc / z;   // FX == FY == 500

    float X = fminf(fmaxf(v0 * fxz + 0.5f * W, -1000.0f), W + 1000.0f);
    float Y = fminf(fmaxf(0.5f * H - v1 * fxz, -1000.0f), H + 1000.0f);

    float sx = fmaxf(s0, 0.001f) * fxz;
    float sy = fmaxf(s1, 0.001f) * fxz;
    float c00 = fminf(fmaxf(sx*sx + 1e-4f, 1e-6f), 1e6f);
    float c11 = fminf(fmaxf(sy*sy + 1e-4f, 1e-6f), 1e6f);

    float sig = 1.0f / (1.0f + __expf(-o));

    // ---- direct stores for the already-unit-stride sections ----
    if (i < N) {
        reinterpret_cast<float4*>(out)[3*Nq + i] =
            make_float4(c00, 1e-6f, 1e-6f, c11);     // cov2d: f4 unit-stride
        out[(size_t)10*N + i] = sig;                  // dword unit-stride
        out[(size_t)11*N + i] = vld;                  // dword unit-stride
    }

    // ---- stage xyz-interleaved outputs to LDS (stride-3: conflict-free) ----
    lout[3*t + 0] = X;
    lout[3*t + 1] = Y;
    lout[3*t + 2] = v2;
    lout[768 + 3*t + 0] = fminf(fmaxf(c0, 0.0f), 1.0f);
    lout[768 + 3*t + 1] = fminf(fmaxf(c1, 0.0f), 1.0f);
    lout[768 + 3*t + 2] = fminf(fmaxf(c2, 0.0f), 1.0f);
    __syncthreads();

    // ---- fully-coalesced float4 stores (waves 0-2 only) ----
    if (t < 192) {
        const int gi = fb + t;
        if (gi < 3 * Nq) {
            reinterpret_cast<float4*>(out)[gi]          = lout4[t];        // proj
            reinterpret_cast<float4*>(out)[7*Nq + gi]   = lout4[192 + t];  // colors
        }
    }
}

extern "C" void kernel_launch(void* const* d_in, const int* in_sizes, int n_in,
                              void* d_out, int out_size, void* d_ws, size_t ws_size,
                              hipStream_t stream) {
    const float4* pos = (const float4*)d_in[0];
    const float4* scl = (const float4*)d_in[1];
    // d_in[2] rotations: UNUSED by reference
    const float4* col = (const float4*)d_in[3];
    const float*  opa = (const float*)d_in[4];
    const float*  vm  = (const float*)d_in[5];
    // d_in[6] projmat: UNUSED by reference
    const int*    pw  = (const int*)d_in[7];
    const int*    ph  = (const int*)d_in[8];

    int N = in_sizes[0] / 3;            // in_sizes[0] = 3N floats
    int blocks = (N + 255) / 256;       // 15625 full blocks at N = 4e6
    gs_project_lds<<<blocks, 256, 0, stream>>>(pos, scl, col, opa, vm, pw, ph,
                                               (float*)d_out, N);
}

// Round 3
// 329.431 us; speedup vs baseline: 1.0691x; 1.0356x over previous
//
#include <hip/hip_runtime.h>
#include <math.h>

// GaussianModel projection pre-pass — v3 (LDS-staged, fully-coalesced) plus
// NONTEMPORAL global loads/stores. Every byte of input/output is touched
// exactly once, so L2 allocation is pure overhead; `nt` bypasses it.
// This is the single change vs the 341.2 µs round-2 kernel, to isolate
// the L2-write-allocate hypothesis.
//
// Reference (JAX):
//   pos_view = clip((p - t) @ R^T, -100, 100)
//   valid    = 0.1 < pos_view.z < 10
//   z        = clip(pos_view.z, 0.1, 10)
//   x        = clip(pv.x*FX/z + W/2, -1000, W+1000)
//   y        = clip(-(pv.y*FY/z) + H/2, -1000, H+1000)
//   cov2d    = [[clip(sx^2+1e-4,1e-6,1e6), 1e-6],[1e-6, clip(sy^2+1e-4,...)]]
//              sx = max(scale.x,1e-3)*FX/z, sy = max(scale.y,1e-3)*FY/z
//   colors clipped to [0,1]; opacity -> sigmoid; mask -> 1.0/0.0
// Outputs concatenated flat (float32):
//   [0,3N) proj | [3N,7N) cov2d | [7N,10N) colors | [10N,11N) opa | [11N,12N) mask

#define FXc 500.0f

typedef float v4f __attribute__((ext_vector_type(4)));

__global__ __launch_bounds__(256) void gs_project_nt(
    const v4f* __restrict__ pos4,
    const v4f* __restrict__ scl4,
    const v4f* __restrict__ col4,
    const float* __restrict__ opa,
    const float* __restrict__ vm,
    const int* __restrict__ pw,
    const int* __restrict__ ph,
    float* __restrict__ out,
    int N)
{
    const int t  = threadIdx.x;
    const int gb = blockIdx.x << 8;        // Gaussian base (256 per block)
    const int i  = gb + t;                 // my Gaussian (global)
    const int fb = blockIdx.x * 192;       // float4 base into 3-float sections
    const int Nq = N >> 2;                 // N/4 = f4 count per N floats

    __shared__ v4f lin4[576];              // pos | scl | col   (9 KB)
    __shared__ v4f lout4[384];             // proj | colc       (6 KB)
    float* lin  = reinterpret_cast<float*>(lin4);
    float* lout = reinterpret_cast<float*>(lout4);

    // ---- stage inputs: fully-coalesced nontemporal float4 loads ----
    if (t < 192) {
        const int gi = fb + t;             // < 3*Nq for all full blocks
        if (gi < 3 * Nq) {
            lin4[t]       = __builtin_nontemporal_load(pos4 + gi);
            lin4[192 + t] = __builtin_nontemporal_load(scl4 + gi);
            lin4[384 + t] = __builtin_nontemporal_load(col4 + gi);
        }
    }
    // opacity: unit-stride dword load, already coalesced
    float o = (i < N) ? __builtin_nontemporal_load(opa + i) : 0.0f;
    __syncthreads();

    // viewmat row-major 4x4; R = vm[:3,:3], tr = vm[:3,3]. Uniform -> s_loads.
    float r00 = vm[0], r01 = vm[1], r02 = vm[2],  t0 = vm[3];
    float r10 = vm[4], r11 = vm[5], r12 = vm[6],  t1 = vm[7];
    float r20 = vm[8], r21 = vm[9], r22 = vm[10], t2 = vm[11];
    float W = (float)(*pw), H = (float)(*ph);

    // ---- gather my Gaussian from LDS (stride-3: conflict-free) ----
    float px = lin[3*t + 0],   py = lin[3*t + 1],   pz = lin[3*t + 2];
    float s0 = lin[768 + 3*t], s1 = lin[768 + 3*t + 1];
    float c0 = lin[1536 + 3*t], c1 = lin[1536 + 3*t + 1], c2 = lin[1536 + 3*t + 2];

    // ---- compute ----
    float dx = px - t0, dy = py - t1, dz = pz - t2;
    float v0 = r00*dx + r01*dy + r02*dz;
    float v1 = r10*dx + r11*dy + r12*dz;
    float v2 = r20*dx + r21*dy + r22*dz;
    v0 = fminf(fmaxf(v0, -100.0f), 100.0f);
    v1 = fminf(fmaxf(v1, -100.0f), 100.0f);
    v2 = fminf(fmaxf(v2, -100.0f), 100.0f);

    float vld = (v2 > 0.1f && v2 < 10.0f) ? 1.0f : 0.0f;
    float z   = fminf(fmaxf(v2, 0.1f), 10.0f);
    float fxz = FXc / z;   // FX == FY == 500

    float X = fminf(fmaxf(v0 * fxz + 0.5f * W, -1000.0f), W + 1000.0f);
    float Y = fminf(fmaxf(0.5f * H - v1 * fxz, -1000.0f), H + 1000.0f);

    float sx = fmaxf(s0, 0.001f) * fxz;
    float sy = fmaxf(s1, 0.001f) * fxz;
    float c00 = fminf(fmaxf(sx*sx + 1e-4f, 1e-6f), 1e6f);
    float c11 = fminf(fmaxf(sy*sy + 1e-4f, 1e-6f), 1e6f);

    float sig = 1.0f / (1.0f + __expf(-o));

    // ---- direct nontemporal stores for the already-unit-stride sections ----
    if (i < N) {
        v4f cv = {c00, 1e-6f, 1e-6f, c11};
        __builtin_nontemporal_store(cv, reinterpret_cast<v4f*>(out) + 3*Nq + i);
        __builtin_nontemporal_store(sig, out + (size_t)10*N + i);
        __builtin_nontemporal_store(vld, out + (size_t)11*N + i);
    }

    // ---- stage xyz-interleaved outputs to LDS (stride-3: conflict-free) ----
    lout[3*t + 0] = X;
    lout[3*t + 1] = Y;
    lout[3*t + 2] = v2;
    lout[768 + 3*t + 0] = fminf(fmaxf(c0, 0.0f), 1.0f);
    lout[768 + 3*t + 1] = fminf(fmaxf(c1, 0.0f), 1.0f);
    lout[768 + 3*t + 2] = fminf(fmaxf(c2, 0.0f), 1.0f);
    __syncthreads();

    // ---- fully-coalesced nontemporal float4 stores (waves 0-2 only) ----
    if (t < 192) {
        const int gi = fb + t;
        if (gi < 3 * Nq) {
            __builtin_nontemporal_store(lout4[t],
                reinterpret_cast<v4f*>(out) + gi);               // proj
            __builtin_nontemporal_store(lout4[192 + t],
                reinterpret_cast<v4f*>(out) + 7*Nq + gi);        // colors
        }
    }
}

extern "C" void kernel_launch(void* const* d_in, const int* in_sizes, int n_in,
                              void* d_out, int out_size, void* d_ws, size_t ws_size,
                              hipStream_t stream) {
    const v4f*  pos = (const v4f*)d_in[0];
    const v4f*  scl = (const v4f*)d_in[1];
    // d_in[2] rotations: UNUSED by reference
    const v4f*  col = (const v4f*)d_in[3];
    const float* opa = (const float*)d_in[4];
    const float* vm  = (const float*)d_in[5];
    // d_in[6] projmat: UNUSED by reference
    const int*   pw  = (const int*)d_in[7];
    const int*   ph  = (const int*)d_in[8];

    int N = in_sizes[0] / 3;            // in_sizes[0] = 3N floats
    int blocks = (N + 255) / 256;       // 15625 full blocks at N = 4e6
    gs_project_nt<<<blocks, 256, 0, stream>>>(pos, scl, col, opa, vm, pw, ph,
                                              (float*)d_out, N);
}